// Round 1
// baseline (359.883 us; speedup 1.0000x reference)
//
#include <hip/hip_runtime.h>
#include <math.h>

constexpr int B_   = 32768;
constexpr int NKPS = 14;
constexpr int DIM  = 42;   // 14*3
constexpr int H1_  = 1024;
constexpr int NDOF = 7;
constexpr int SPLIT = 2;          // threads per batch row (split hidden layer)
constexpr int JH    = H1_ / SPLIT;

// Jacobi rotation on symmetric 3x3 for pivot (p,q), r = third index.
// app=a_pp, aqq=a_qq, apq=a_pq, arp=a_rp, arq=a_rq; V columns p,q (rows 0..2).
#define JROT(app, aqq, apq, arp, arq, v0p, v0q, v1p, v1q, v2p, v2q) do { \
    double _apq = (apq); \
    if (fabs(_apq) > 1e-300) { \
        double _tau = ((aqq) - (app)) / (2.0 * _apq); \
        double _t = ((_tau >= 0.0) ? 1.0 : -1.0) / (fabs(_tau) + sqrt(1.0 + _tau*_tau)); \
        double _c = 1.0 / sqrt(1.0 + _t*_t); \
        double _s = _t * _c; \
        (app) -= _t * _apq; \
        (aqq) += _t * _apq; \
        (apq) = 0.0; \
        { double _rp = (arp), _rq = (arq); \
          (arp) = _c*_rp - _s*_rq; (arq) = _s*_rp + _c*_rq; } \
        { double _v = (v0p); (v0p) = _c*_v - _s*(v0q); (v0q) = _s*_v + _c*(v0q); } \
        { double _v = (v1p); (v1p) = _c*_v - _s*(v1q); (v1q) = _s*_v + _c*(v1q); } \
        { double _v = (v2p); (v2p) = _c*_v - _s*(v2q); (v2q) = _s*_v + _c*(v2q); } \
    } \
} while (0)

#define SWAP_EIG(ea, eb, va0, vb0, va1, vb1, va2, vb2) do { \
    double _tm; \
    _tm = (ea); (ea) = (eb); (eb) = _tm; \
    _tm = (va0); (va0) = (vb0); (vb0) = _tm; \
    _tm = (va1); (va1) = (vb1); (vb1) = _tm; \
    _tm = (va2); (va2) = (vb2); (vb2) = _tm; \
} while (0)

__global__ __launch_bounds__(256)
void fk_fused(const float* __restrict__ joints,
              const float* __restrict__ W1,
              const float* __restrict__ b1,
              const float* __restrict__ W2,
              const float* __restrict__ b2,
              float* __restrict__ out)
{
    const int T = blockIdx.x * blockDim.x + threadIdx.x;
    const int b = T >> 1;          // batch row
    const int half = T & 1;        // which half of the hidden layer
    if (b >= B_) return;

    // ---- load joints row, build normalized x (= Q for Kabsch) ----
    const float* jr = joints + (long)b * DIM;
    const float j0x = jr[0], j0y = jr[1], j0z = jr[2];
    float q[DIM];
#pragma unroll
    for (int k = 0; k < NKPS; ++k) {
        q[3*k+0] = jr[3*k+0] - j0x;
        q[3*k+1] = jr[3*k+1] - j0y;
        q[3*k+2] = jr[3*k+2] - j0z;
    }

    // ---- MLP: h = relu(x@W1 + b1); ang = h@W2 + b2 (this thread: JH cols) ----
    float ang[NDOF];
#pragma unroll
    for (int d = 0; d < NDOF; ++d) ang[d] = half ? 0.0f : b2[d];

    const int jbase = half * JH;
    for (int jj = 0; jj < JH; jj += 8) {
        const int j = jbase + jj;
        float h[8];
#pragma unroll
        for (int u = 0; u < 8; ++u) h[u] = b1[j + u];
#pragma unroll
        for (int k = 0; k < DIM; ++k) {
            const float xk = q[k];
            const float* w = W1 + (long)k * H1_ + j;   // wave-uniform -> s_load
#pragma unroll
            for (int u = 0; u < 8; ++u) h[u] = fmaf(xk, w[u], h[u]);
        }
#pragma unroll
        for (int u = 0; u < 8; ++u) {
            const float hu = fmaxf(h[u], 0.0f);
            const float* w2 = W2 + (long)(j + u) * NDOF;  // wave-uniform
#pragma unroll
            for (int d = 0; d < NDOF; ++d) ang[d] = fmaf(hu, w2[d], ang[d]);
        }
    }
    // combine halves (lane pairs 2t / 2t+1)
#pragma unroll
    for (int d = 0; d < NDOF; ++d) ang[d] += __shfl_xor(ang[d], 1, 64);

    // ---- forward kinematics + on-the-fly Kabsch accumulators ----
    float R00=1.f,R01=0.f,R02=0.f, R10=0.f,R11=1.f,R12=0.f, R20=0.f,R21=0.f,R22=1.f;
    float px=0.f, py=0.f, pz=0.f;
    float Hr00=0.f,Hr01=0.f,Hr02=0.f,Hr10=0.f,Hr11=0.f,Hr12=0.f,Hr20=0.f,Hr21=0.f,Hr22=0.f;
    float sPx=0.f, sPy=0.f, sPz=0.f;
    const float LL[NDOF] = {0.333f,0.316f,0.384f,0.088f,0.107f,0.103f,0.1f};

#pragma unroll
    for (int j = 0; j < NDOF; ++j) {
        float s, c;
        sincosf(ang[j], &s, &c);
        if ((j & 1) == 0) {   // rot_z: col0' = c*col0 + s*col1 ; col1' = -s*col0 + c*col1
            float a0=R00, a1=R01; R00 = c*a0 + s*a1; R01 = c*a1 - s*a0;
            float b0=R10, b1v=R11; R10 = c*b0 + s*b1v; R11 = c*b1v - s*b0;
            float c0=R20, c1=R21; R20 = c*c0 + s*c1; R21 = c*c1 - s*c0;
        } else {              // rot_y: col0' = c*col0 - s*col2 ; col2' = s*col0 + c*col2
            float a0=R00, a2=R02; R00 = c*a0 - s*a2; R02 = s*a0 + c*a2;
            float b0=R10, b2v=R12; R10 = c*b0 - s*b2v; R12 = s*b0 + c*b2v;
            float c0=R20, c2=R22; R20 = c*c0 - s*c2; R22 = s*c0 + c*c2;
        }
        px = fmaf(LL[j], R02, px);
        py = fmaf(LL[j], R12, py);
        pz = fmaf(LL[j], R22, pz);

        // point n = 2j : P = p
        {
            const float qx = q[6*j+0], qy = q[6*j+1], qz = q[6*j+2];
            sPx += px; sPy += py; sPz += pz;
            Hr00 = fmaf(px, qx, Hr00); Hr01 = fmaf(px, qy, Hr01); Hr02 = fmaf(px, qz, Hr02);
            Hr10 = fmaf(py, qx, Hr10); Hr11 = fmaf(py, qy, Hr11); Hr12 = fmaf(py, qz, Hr12);
            Hr20 = fmaf(pz, qx, Hr20); Hr21 = fmaf(pz, qy, Hr21); Hr22 = fmaf(pz, qz, Hr22);
        }
        // point n = 2j+1 : P = p + 0.05*col0(R)
        {
            const float ox = fmaf(0.05f, R00, px);
            const float oy = fmaf(0.05f, R10, py);
            const float oz = fmaf(0.05f, R20, pz);
            const float qx = q[6*j+3], qy = q[6*j+4], qz = q[6*j+5];
            sPx += ox; sPy += oy; sPz += oz;
            Hr00 = fmaf(ox, qx, Hr00); Hr01 = fmaf(ox, qy, Hr01); Hr02 = fmaf(ox, qz, Hr02);
            Hr10 = fmaf(oy, qx, Hr10); Hr11 = fmaf(oy, qy, Hr11); Hr12 = fmaf(oy, qz, Hr12);
            Hr20 = fmaf(oz, qx, Hr20); Hr21 = fmaf(oz, qy, Hr21); Hr22 = fmaf(oz, qz, Hr22);
        }
    }

    // sum of Q
    float sQx = 0.f, sQy = 0.f, sQz = 0.f;
#pragma unroll
    for (int n = 0; n < NKPS; ++n) { sQx += q[3*n+0]; sQy += q[3*n+1]; sQz += q[3*n+2]; }

    // ---- Kabsch in f64: H = Hr - 14*cp*cq^T ; M = H^T H ; Jacobi eigen ----
    const double inv14 = 1.0 / 14.0;
    const double cpx = (double)sPx * inv14, cpy = (double)sPy * inv14, cpz = (double)sPz * inv14;
    const double cqx = (double)sQx * inv14, cqy = (double)sQy * inv14, cqz = (double)sQz * inv14;

    const double h00 = (double)Hr00 - 14.0*cpx*cqx, h01 = (double)Hr01 - 14.0*cpx*cqy, h02 = (double)Hr02 - 14.0*cpx*cqz;
    const double h10 = (double)Hr10 - 14.0*cpy*cqx, h11 = (double)Hr11 - 14.0*cpy*cqy, h12 = (double)Hr12 - 14.0*cpy*cqz;
    const double h20 = (double)Hr20 - 14.0*cpz*cqx, h21 = (double)Hr21 - 14.0*cpz*cqy, h22 = (double)Hr22 - 14.0*cpz*cqz;

    // M = H^T H (symmetric)
    double m00 = h00*h00 + h10*h10 + h20*h20;
    double m01 = h00*h01 + h10*h11 + h20*h21;
    double m02 = h00*h02 + h10*h12 + h20*h22;
    double m11 = h01*h01 + h11*h11 + h21*h21;
    double m12 = h01*h02 + h11*h12 + h21*h22;
    double m22 = h02*h02 + h12*h12 + h22*h22;

    double v00=1.0, v01=0.0, v02=0.0;
    double v10=0.0, v11=1.0, v12=0.0;
    double v20=0.0, v21=0.0, v22=1.0;

#pragma unroll
    for (int sw = 0; sw < 5; ++sw) {
        JROT(m00, m11, m01, m02, m12, v00, v01, v10, v11, v20, v21); // pivot (0,1), r=2
        JROT(m00, m22, m02, m01, m12, v00, v02, v10, v12, v20, v22); // pivot (0,2), r=1
        JROT(m11, m22, m12, m01, m02, v01, v02, v11, v12, v21, v22); // pivot (1,2), r=0
    }

    double e0 = m00, e1 = m11, e2 = m22;
    if (e0 < e1) SWAP_EIG(e0, e1, v00, v01, v10, v11, v20, v21);
    if (e0 < e2) SWAP_EIG(e0, e2, v00, v02, v10, v12, v20, v22);
    if (e1 < e2) SWAP_EIG(e1, e2, v01, v02, v11, v12, v21, v22);

    const double s0 = sqrt(fmax(e0, 0.0));
    const double s1 = sqrt(fmax(e1, 0.0));
    const double s2 = sqrt(fmax(e2, 0.0));

    const double det = h00*(h11*h22 - h12*h21) - h01*(h10*h22 - h12*h20) + h02*(h10*h21 - h11*h20);
    const double dsg = (det >= 0.0) ? 1.0 : -1.0;

    const double tiny = 1e-30;
    const double g0 = 1.0 / fmax(s0, tiny);
    const double g1 = 1.0 / fmax(s1, tiny);
    const double g2 = dsg / fmax(s2, tiny);

    // K = V diag(g) V^T (symmetric)
    const double K00 = g0*v00*v00 + g1*v01*v01 + g2*v02*v02;
    const double K01 = g0*v00*v10 + g1*v01*v11 + g2*v02*v12;
    const double K02 = g0*v00*v20 + g1*v01*v21 + g2*v02*v22;
    const double K11 = g0*v10*v10 + g1*v11*v11 + g2*v12*v12;
    const double K12 = g0*v10*v20 + g1*v11*v21 + g2*v12*v22;
    const double K22 = g0*v20*v20 + g1*v21*v21 + g2*v22*v22;

    // R = K * H^T  (R[i][j] = sum_l K[i][l] * H[j][l])
    const double r00 = K00*h00 + K01*h01 + K02*h02;
    const double r01 = K00*h10 + K01*h11 + K02*h12;
    const double r02 = K00*h20 + K01*h21 + K02*h22;
    const double r10 = K01*h00 + K11*h01 + K12*h02;
    const double r11 = K01*h10 + K11*h11 + K12*h12;
    const double r12 = K01*h20 + K11*h21 + K12*h22;
    const double r20 = K02*h00 + K12*h01 + K22*h02;
    const double r21 = K02*h10 + K12*h11 + K22*h12;
    const double r22 = K02*h20 + K12*h21 + K22*h22;

    // t = cq - R*cp + joints[b,0]
    const double tx = cqx - (r00*cpx + r01*cpy + r02*cpz) + (double)j0x;
    const double ty = cqy - (r10*cpx + r11*cpy + r12*cpz) + (double)j0y;
    const double tz = cqz - (r20*cpx + r21*cpy + r22*cpz) + (double)j0z;

    if (half == 0) {
        float* ao = out + (long)b * NDOF;
#pragma unroll
        for (int d = 0; d < NDOF; ++d) ao[d] = ang[d];

        float* po = out + (long)B_ * NDOF + (long)b * 16;
        po[0]  = (float)r00; po[1]  = (float)r01; po[2]  = (float)r02; po[3]  = (float)tx;
        po[4]  = (float)r10; po[5]  = (float)r11; po[6]  = (float)r12; po[7]  = (float)ty;
        po[8]  = (float)r20; po[9]  = (float)r21; po[10] = (float)r22; po[11] = (float)tz;
        po[12] = 0.f; po[13] = 0.f; po[14] = 0.f; po[15] = 1.f;
    }
}

extern "C" void kernel_launch(void* const* d_in, const int* in_sizes, int n_in,
                              void* d_out, int out_size, void* d_ws, size_t ws_size,
                              hipStream_t stream) {
    const float* joints = (const float*)d_in[0];
    const float* W1     = (const float*)d_in[1];
    const float* b1     = (const float*)d_in[2];
    const float* W2     = (const float*)d_in[3];
    const float* b2     = (const float*)d_in[4];
    float* out = (float*)d_out;

    const int threads = 256;
    const int total   = B_ * SPLIT;
    const int blocks  = (total + threads - 1) / threads;
    hipLaunchKernelGGL(fk_fused, dim3(blocks), dim3(threads), 0, stream,
                       joints, W1, b1, W2, b2, out);
}

// Round 2
// 62.019 us; speedup vs baseline: 5.8028x; 5.8028x over previous
//
#include <hip/hip_runtime.h>
#include <math.h>

typedef __attribute__((ext_vector_type(8))) short short8;
typedef __attribute__((ext_vector_type(4))) float f32x4;

constexpr int B_   = 32768;
constexpr int NKPS = 14;
constexpr int DIM  = 42;
constexpr int H1_  = 1024;
constexpr int NDOF = 7;

__device__ __forceinline__ unsigned short f2bf(float f) {
    unsigned u = __float_as_uint(f);
    u += 0x7FFFu + ((u >> 16) & 1u);
    return (unsigned short)(u >> 16);
}
__device__ __forceinline__ float bf2f(unsigned short h) {
    return __uint_as_float(((unsigned)h) << 16);
}

// ---------------------------------------------------------------------------
// K0: pack B = [W1_hi ; W1_hi ; W1_lo ; b1_hi ; b1_lo] (K=128 x N=1024 bf16)
// into per-lane MFMA fragment order: element (ks, ntile, lane, j) at
// B1[((ks*64 + ntile)*64 + lane)*8 + j] holds B[k = ks*32+(lane>>4)*8+j]
//                                          [n = ntile*16+(lane&15)].
// Also pads W2 [1024][7] -> W2p [1024][8] f32.
// ---------------------------------------------------------------------------
__global__ __launch_bounds__(256)
void prep_kernel(const float* __restrict__ W1, const float* __restrict__ b1,
                 const float* __restrict__ W2,
                 unsigned short* __restrict__ B1, float* __restrict__ W2p)
{
    const int T = blockIdx.x * 256 + threadIdx.x;
    if (T < 16384) {
        const int lane  = T & 63;
        const int ntile = (T >> 6) & 63;
        const int ks    = T >> 12;
        const int n     = ntile * 16 + (lane & 15);
        const int kbase = ks * 32 + ((lane >> 4) << 3);
        short8 s;
#pragma unroll
        for (int j = 0; j < 8; ++j) {
            const int k = kbase + j;
            unsigned short r;
            if (k < 42) {
                r = f2bf(W1[k * H1_ + n]);
            } else if (k < 84) {
                r = f2bf(W1[(k - 42) * H1_ + n]);
            } else if (k < 126) {
                const float x = W1[(k - 84) * H1_ + n];
                const unsigned short hi = f2bf(x);
                r = f2bf(x - bf2f(hi));
            } else if (k == 126) {
                r = f2bf(b1[n]);
            } else {
                const float x = b1[n];
                const unsigned short hi = f2bf(x);
                r = f2bf(x - bf2f(hi));
            }
            s[j] = (short)r;
        }
        *((short8*)(B1 + (long)T * 8)) = s;
    } else if (T < 16384 + 1024) {
        const int n = T - 16384;
#pragma unroll
        for (int d = 0; d < 7; ++d) W2p[n * 8 + d] = W2[n * 7 + d];
        W2p[n * 8 + 7] = 0.f;
    }
}

// ---------------------------------------------------------------------------
// K1: MLP via MFMA. Block = 512 thr (8 waves), M-tile = 32 rows, N = 1024.
// Wave w handles 128 cols (ntiles w*8 .. w*8+7). GEMM2 (h@W2) in f32 VALU.
// Writes angles [B,7] to outAng.
// ---------------------------------------------------------------------------
__global__ __launch_bounds__(512, 2)
void mlp_kernel(const float* __restrict__ joints,
                const unsigned short* __restrict__ B1,
                const float* __restrict__ W2p,
                const float* __restrict__ b2,
                float* __restrict__ outAng)
{
    __shared__ unsigned short Alds[32][136];      // 32 rows x K=128 (+8 pad)
    __shared__ float angred[8][32][8];            // per-wave angle partials

    const int  tid = threadIdx.x;
    const long bm  = (long)blockIdx.x * 32;

    // ---- stage A: x split [x_hi | x_lo | x_hi | 1 | 1] as bf16 ----
    {
        const int r   = tid >> 4;     // 0..31
        const int c16 = tid & 15;     // 16 groups of 8 k
        const float* jr = joints + (bm + r) * DIM;
        short8 s;
#pragma unroll
        for (int j = 0; j < 8; ++j) {
            const int k = c16 * 8 + j;
            unsigned short v;
            if (k >= 126) {
                v = 0x3F80;  // bf16(1.0)
            } else {
                const int ksrc = (k < 42) ? k : (k < 84 ? k - 42 : k - 84);
                const float x = jr[ksrc] - jr[ksrc % 3];
                const unsigned short hi = f2bf(x);
                v = (k >= 42 && k < 84) ? f2bf(x - bf2f(hi)) : hi;
            }
            s[j] = (short)v;
        }
        *((short8*)&Alds[r][c16 * 8]) = s;
    }
    __syncthreads();

    const int lane = tid & 63;
    const int w    = tid >> 6;     // wave 0..7
    const int l4   = lane >> 4;    // 0..3
    const int lm   = lane & 15;

    // ---- A fragments from LDS ----
    short8 a[2][4];
#pragma unroll
    for (int mt = 0; mt < 2; ++mt)
#pragma unroll
        for (int ks = 0; ks < 4; ++ks)
            a[mt][ks] = *((const short8*)&Alds[mt * 16 + lm][ks * 32 + l4 * 8]);

    f32x4 acc[2][8];
#pragma unroll
    for (int mt = 0; mt < 2; ++mt)
#pragma unroll
        for (int nt = 0; nt < 8; ++nt)
            acc[mt][nt] = (f32x4){0.f, 0.f, 0.f, 0.f};

    const short8* Bf = (const short8*)B1;
#pragma unroll
    for (int nt = 0; nt < 8; ++nt) {
        const int ntile = w * 8 + nt;
#pragma unroll
        for (int ks = 0; ks < 4; ++ks) {
            const short8 bfr = Bf[(ks * 64 + ntile) * 64 + lane];
            acc[0][nt] = __builtin_amdgcn_mfma_f32_16x16x32_bf16(a[0][ks], bfr, acc[0][nt], 0, 0, 0);
            acc[1][nt] = __builtin_amdgcn_mfma_f32_16x16x32_bf16(a[1][ks], bfr, acc[1][nt], 0, 0, 0);
        }
    }

    // ---- GEMM2 in f32: ang_partial[m][d] += relu(h[m][col]) * W2[col][d] ----
    float angp[2][4][7];
#pragma unroll
    for (int mt = 0; mt < 2; ++mt)
#pragma unroll
        for (int r = 0; r < 4; ++r)
#pragma unroll
            for (int d = 0; d < 7; ++d) angp[mt][r][d] = 0.f;

#pragma unroll
    for (int nt = 0; nt < 8; ++nt) {
        const int col = (w * 8 + nt) * 16 + lm;
        const f32x4 wa = *((const f32x4*)(W2p + (long)col * 8));
        const f32x4 wb = *((const f32x4*)(W2p + (long)col * 8 + 4));
        const float wv[7] = {wa[0], wa[1], wa[2], wa[3], wb[0], wb[1], wb[2]};
#pragma unroll
        for (int mt = 0; mt < 2; ++mt)
#pragma unroll
            for (int r = 0; r < 4; ++r) {
                const float h = fmaxf(acc[mt][nt][r], 0.f);
#pragma unroll
                for (int d = 0; d < 7; ++d)
                    angp[mt][r][d] = fmaf(h, wv[d], angp[mt][r][d]);
            }
    }

    // reduce over the 16 lanes sharing a row-group (xor bits 0..3)
#pragma unroll
    for (int mt = 0; mt < 2; ++mt)
#pragma unroll
        for (int r = 0; r < 4; ++r)
#pragma unroll
            for (int d = 0; d < 7; ++d) {
                float v = angp[mt][r][d];
                v += __shfl_xor(v, 1, 64);
                v += __shfl_xor(v, 2, 64);
                v += __shfl_xor(v, 4, 64);
                v += __shfl_xor(v, 8, 64);
                angp[mt][r][d] = v;
            }

    if (lm == 0) {
#pragma unroll
        for (int mt = 0; mt < 2; ++mt)
#pragma unroll
            for (int r = 0; r < 4; ++r)
#pragma unroll
                for (int d = 0; d < 7; ++d)
                    angred[w][mt * 16 + l4 * 4 + r][d] = angp[mt][r][d];
    }
    __syncthreads();

    if (tid < 224) {
        const int m = tid / 7, d = tid % 7;
        float s = b2[d];
#pragma unroll
        for (int ww = 0; ww < 8; ++ww) s += angred[ww][m][d];
        outAng[(bm + m) * 7 + d] = s;
    }
}

// ---------------------------------------------------------------------------
// K2: per-row FK + Kabsch (f64 Jacobi), reads angles from d_out.
// ---------------------------------------------------------------------------
#define JROT(app, aqq, apq, arp, arq, v0p, v0q, v1p, v1q, v2p, v2q) do { \
    double _apq = (apq); \
    if (fabs(_apq) > 1e-300) { \
        double _tau = ((aqq) - (app)) / (2.0 * _apq); \
        double _t = ((_tau >= 0.0) ? 1.0 : -1.0) / (fabs(_tau) + sqrt(1.0 + _tau*_tau)); \
        double _c = 1.0 / sqrt(1.0 + _t*_t); \
        double _s = _t * _c; \
        (app) -= _t * _apq; \
        (aqq) += _t * _apq; \
        (apq) = 0.0; \
        { double _rp = (arp), _rq = (arq); \
          (arp) = _c*_rp - _s*_rq; (arq) = _s*_rp + _c*_rq; } \
        { double _v = (v0p); (v0p) = _c*_v - _s*(v0q); (v0q) = _s*_v + _c*(v0q); } \
        { double _v = (v1p); (v1p) = _c*_v - _s*(v1q); (v1q) = _s*_v + _c*(v1q); } \
        { double _v = (v2p); (v2p) = _c*_v - _s*(v2q); (v2q) = _s*_v + _c*(v2q); } \
    } \
} while (0)

#define SWAP_EIG(ea, eb, va0, vb0, va1, vb1, va2, vb2) do { \
    double _tm; \
    _tm = (ea); (ea) = (eb); (eb) = _tm; \
    _tm = (va0); (va0) = (vb0); (vb0) = _tm; \
    _tm = (va1); (va1) = (vb1); (vb1) = _tm; \
    _tm = (va2); (va2) = (vb2); (vb2) = _tm; \
} while (0)

__global__ __launch_bounds__(256)
void fk_kernel(const float* __restrict__ joints,
               const float* __restrict__ ang_in,
               float* __restrict__ out)
{
    const int b = blockIdx.x * 256 + threadIdx.x;
    if (b >= B_) return;

    const float* jr = joints + (long)b * DIM;
    const float j0x = jr[0], j0y = jr[1], j0z = jr[2];
    float q[DIM];
#pragma unroll
    for (int k = 0; k < NKPS; ++k) {
        q[3*k+0] = jr[3*k+0] - j0x;
        q[3*k+1] = jr[3*k+1] - j0y;
        q[3*k+2] = jr[3*k+2] - j0z;
    }

    float ang[NDOF];
#pragma unroll
    for (int d = 0; d < NDOF; ++d) ang[d] = ang_in[(long)b * NDOF + d];

    float R00=1.f,R01=0.f,R02=0.f, R10=0.f,R11=1.f,R12=0.f, R20=0.f,R21=0.f,R22=1.f;
    float px=0.f, py=0.f, pz=0.f;
    float Hr00=0.f,Hr01=0.f,Hr02=0.f,Hr10=0.f,Hr11=0.f,Hr12=0.f,Hr20=0.f,Hr21=0.f,Hr22=0.f;
    float sPx=0.f, sPy=0.f, sPz=0.f;
    const float LL[NDOF] = {0.333f,0.316f,0.384f,0.088f,0.107f,0.103f,0.1f};

#pragma unroll
    for (int j = 0; j < NDOF; ++j) {
        float s, c;
        sincosf(ang[j], &s, &c);
        if ((j & 1) == 0) {
            float a0=R00, a1=R01; R00 = c*a0 + s*a1; R01 = c*a1 - s*a0;
            float b0=R10, b1v=R11; R10 = c*b0 + s*b1v; R11 = c*b1v - s*b0;
            float c0=R20, c1=R21; R20 = c*c0 + s*c1; R21 = c*c1 - s*c0;
        } else {
            float a0=R00, a2=R02; R00 = c*a0 - s*a2; R02 = s*a0 + c*a2;
            float b0=R10, b2v=R12; R10 = c*b0 - s*b2v; R12 = s*b0 + c*b2v;
            float c0=R20, c2=R22; R20 = c*c0 - s*c2; R22 = s*c0 + c*c2;
        }
        px = fmaf(LL[j], R02, px);
        py = fmaf(LL[j], R12, py);
        pz = fmaf(LL[j], R22, pz);
        {
            const float qx = q[6*j+0], qy = q[6*j+1], qz = q[6*j+2];
            sPx += px; sPy += py; sPz += pz;
            Hr00 = fmaf(px, qx, Hr00); Hr01 = fmaf(px, qy, Hr01); Hr02 = fmaf(px, qz, Hr02);
            Hr10 = fmaf(py, qx, Hr10); Hr11 = fmaf(py, qy, Hr11); Hr12 = fmaf(py, qz, Hr12);
            Hr20 = fmaf(pz, qx, Hr20); Hr21 = fmaf(pz, qy, Hr21); Hr22 = fmaf(pz, qz, Hr22);
        }
        {
            const float ox = fmaf(0.05f, R00, px);
            const float oy = fmaf(0.05f, R10, py);
            const float oz = fmaf(0.05f, R20, pz);
            const float qx = q[6*j+3], qy = q[6*j+4], qz = q[6*j+5];
            sPx += ox; sPy += oy; sPz += oz;
            Hr00 = fmaf(ox, qx, Hr00); Hr01 = fmaf(ox, qy, Hr01); Hr02 = fmaf(ox, qz, Hr02);
            Hr10 = fmaf(oy, qx, Hr10); Hr11 = fmaf(oy, qy, Hr11); Hr12 = fmaf(oy, qz, Hr12);
            Hr20 = fmaf(oz, qx, Hr20); Hr21 = fmaf(oz, qy, Hr21); Hr22 = fmaf(oz, qz, Hr22);
        }
    }

    float sQx = 0.f, sQy = 0.f, sQz = 0.f;
#pragma unroll
    for (int n = 0; n < NKPS; ++n) { sQx += q[3*n+0]; sQy += q[3*n+1]; sQz += q[3*n+2]; }

    const double inv14 = 1.0 / 14.0;
    const double cpx = (double)sPx * inv14, cpy = (double)sPy * inv14, cpz = (double)sPz * inv14;
    const double cqx = (double)sQx * inv14, cqy = (double)sQy * inv14, cqz = (double)sQz * inv14;

    const double h00 = (double)Hr00 - 14.0*cpx*cqx, h01 = (double)Hr01 - 14.0*cpx*cqy, h02 = (double)Hr02 - 14.0*cpx*cqz;
    const double h10 = (double)Hr10 - 14.0*cpy*cqx, h11 = (double)Hr11 - 14.0*cpy*cqy, h12 = (double)Hr12 - 14.0*cpy*cqz;
    const double h20 = (double)Hr20 - 14.0*cpz*cqx, h21 = (double)Hr21 - 14.0*cpz*cqy, h22 = (double)Hr22 - 14.0*cpz*cqz;

    double m00 = h00*h00 + h10*h10 + h20*h20;
    double m01 = h00*h01 + h10*h11 + h20*h21;
    double m02 = h00*h02 + h10*h12 + h20*h22;
    double m11 = h01*h01 + h11*h11 + h21*h21;
    double m12 = h01*h02 + h11*h12 + h21*h22;
    double m22 = h02*h02 + h12*h12 + h22*h22;

    double v00=1.0, v01=0.0, v02=0.0;
    double v10=0.0, v11=1.0, v12=0.0;
    double v20=0.0, v21=0.0, v22=1.0;

#pragma unroll
    for (int sw = 0; sw < 5; ++sw) {
        JROT(m00, m11, m01, m02, m12, v00, v01, v10, v11, v20, v21);
        JROT(m00, m22, m02, m01, m12, v00, v02, v10, v12, v20, v22);
        JROT(m11, m22, m12, m01, m02, v01, v02, v11, v12, v21, v22);
    }

    double e0 = m00, e1 = m11, e2 = m22;
    if (e0 < e1) SWAP_EIG(e0, e1, v00, v01, v10, v11, v20, v21);
    if (e0 < e2) SWAP_EIG(e0, e2, v00, v02, v10, v12, v20, v22);
    if (e1 < e2) SWAP_EIG(e1, e2, v01, v02, v11, v12, v21, v22);

    const double s0 = sqrt(fmax(e0, 0.0));
    const double s1 = sqrt(fmax(e1, 0.0));
    const double s2 = sqrt(fmax(e2, 0.0));

    const double det = h00*(h11*h22 - h12*h21) - h01*(h10*h22 - h12*h20) + h02*(h10*h21 - h11*h20);
    const double dsg = (det >= 0.0) ? 1.0 : -1.0;

    const double tiny = 1e-30;
    const double g0 = 1.0 / fmax(s0, tiny);
    const double g1 = 1.0 / fmax(s1, tiny);
    const double g2 = dsg / fmax(s2, tiny);

    const double K00 = g0*v00*v00 + g1*v01*v01 + g2*v02*v02;
    const double K01 = g0*v00*v10 + g1*v01*v11 + g2*v02*v12;
    const double K02 = g0*v00*v20 + g1*v01*v21 + g2*v02*v22;
    const double K11 = g0*v10*v10 + g1*v11*v11 + g2*v12*v12;
    const double K12 = g0*v10*v20 + g1*v11*v21 + g2*v12*v22;
    const double K22 = g0*v20*v20 + g1*v21*v21 + g2*v22*v22;

    const double r00 = K00*h00 + K01*h01 + K02*h02;
    const double r01 = K00*h10 + K01*h11 + K02*h12;
    const double r02 = K00*h20 + K01*h21 + K02*h22;
    const double r10 = K01*h00 + K11*h01 + K12*h02;
    const double r11 = K01*h10 + K11*h11 + K12*h12;
    const double r12 = K01*h20 + K11*h21 + K12*h22;
    const double r20 = K02*h00 + K12*h01 + K22*h02;
    const double r21 = K02*h10 + K12*h11 + K22*h12;
    const double r22 = K02*h20 + K12*h21 + K22*h22;

    const double tx = cqx - (r00*cpx + r01*cpy + r02*cpz) + (double)j0x;
    const double ty = cqy - (r10*cpx + r11*cpy + r12*cpz) + (double)j0y;
    const double tz = cqz - (r20*cpx + r21*cpy + r22*cpz) + (double)j0z;

    float* po = out + (long)B_ * NDOF + (long)b * 16;
    po[0]  = (float)r00; po[1]  = (float)r01; po[2]  = (float)r02; po[3]  = (float)tx;
    po[4]  = (float)r10; po[5]  = (float)r11; po[6]  = (float)r12; po[7]  = (float)ty;
    po[8]  = (float)r20; po[9]  = (float)r21; po[10] = (float)r22; po[11] = (float)tz;
    po[12] = 0.f; po[13] = 0.f; po[14] = 0.f; po[15] = 1.f;
}

extern "C" void kernel_launch(void* const* d_in, const int* in_sizes, int n_in,
                              void* d_out, int out_size, void* d_ws, size_t ws_size,
                              hipStream_t stream) {
    const float* joints = (const float*)d_in[0];
    const float* W1     = (const float*)d_in[1];
    const float* b1     = (const float*)d_in[2];
    const float* W2     = (const float*)d_in[3];
    const float* b2     = (const float*)d_in[4];
    float* out = (float*)d_out;

    unsigned short* B1  = (unsigned short*)d_ws;                     // 256 KB
    float*          W2p = (float*)((char*)d_ws + 262144);            // 32 KB

    // K0: pack weights (16384 B1 fragments + 1024 W2 rows)
    hipLaunchKernelGGL(prep_kernel, dim3(68), dim3(256), 0, stream,
                       W1, b1, W2, B1, W2p);

    // K1: MLP -> angles (written to out[0 .. B*7))
    hipLaunchKernelGGL(mlp_kernel, dim3(B_ / 32), dim3(512), 0, stream,
                       joints, B1, W2p, b2, out);

    // K2: FK + Kabsch -> pose (written to out[B*7 ..))
    hipLaunchKernelGGL(fk_kernel, dim3(B_ / 256), dim3(256), 0, stream,
                       joints, out, out);
}

// Round 3
// 50.540 us; speedup vs baseline: 7.1208x; 1.2271x over previous
//
#include <hip/hip_runtime.h>
#include <math.h>

typedef __attribute__((ext_vector_type(8))) short short8;
typedef __attribute__((ext_vector_type(4))) float f32x4;
typedef __attribute__((ext_vector_type(2))) float f32x2;

constexpr int B_   = 32768;
constexpr int NKPS = 14;
constexpr int DIM  = 42;
constexpr int H1_  = 1024;
constexpr int NDOF = 7;

__device__ __forceinline__ unsigned short f2bf(float f) {
    unsigned u = __float_as_uint(f);
    u += 0x7FFFu + ((u >> 16) & 1u);
    return (unsigned short)(u >> 16);
}
__device__ __forceinline__ float bf2f(unsigned short h) {
    return __uint_as_float(((unsigned)h) << 16);
}

// ---------------------------------------------------------------------------
// K0: pack B = [W1_hi ; W1_hi ; W1_lo ; b1_hi ; b1_lo] (K=128 x N=1024 bf16)
// in per-lane fragment order: B1[((ks*64+nt)*64+lane)*8+j] =
//   B[k = ks*32+(lane>>4)*8+j][n = nt*16+(lane&15)].
// Also pads W2 [1024][7] -> W2p [1024][8] f32.
// ---------------------------------------------------------------------------
__global__ __launch_bounds__(256)
void prep_kernel(const float* __restrict__ W1, const float* __restrict__ b1,
                 const float* __restrict__ W2,
                 unsigned short* __restrict__ B1, float* __restrict__ W2p)
{
    const int T = blockIdx.x * 256 + threadIdx.x;
    if (T < 16384) {
        const int lane  = T & 63;
        const int ntile = (T >> 6) & 63;
        const int ks    = T >> 12;
        const int n     = ntile * 16 + (lane & 15);
        const int kbase = ks * 32 + ((lane >> 4) << 3);
        short8 s;
#pragma unroll
        for (int j = 0; j < 8; ++j) {
            const int k = kbase + j;
            unsigned short r;
            if (k < 42) {
                r = f2bf(W1[k * H1_ + n]);
            } else if (k < 84) {
                r = f2bf(W1[(k - 42) * H1_ + n]);
            } else if (k < 126) {
                const float x = W1[(k - 84) * H1_ + n];
                const unsigned short hi = f2bf(x);
                r = f2bf(x - bf2f(hi));
            } else if (k == 126) {
                r = f2bf(b1[n]);
            } else {
                const float x = b1[n];
                const unsigned short hi = f2bf(x);
                r = f2bf(x - bf2f(hi));
            }
            s[j] = (short)r;
        }
        *((short8*)(B1 + (long)T * 8)) = s;
    } else if (T < 16384 + 1024) {
        const int n = T - 16384;
#pragma unroll
        for (int d = 0; d < 7; ++d) W2p[n * 8 + d] = W2[n * 7 + d];
        W2p[n * 8 + 7] = 0.f;
    }
}

// ---------------------------------------------------------------------------
// K1: MLP via MFMA with SWAPPED operands: acc = mfma(W1frag, xfrag) gives
// C[n][m] (lane: m = lane&15, n = (lane>>4)*4+reg) so the hidden-dim (1024)
// reduction for angles is within-lane. Epilogue folded into the nt loop.
// ---------------------------------------------------------------------------
__global__ __launch_bounds__(512, 4)
void mlp_kernel(const float* __restrict__ joints,
                const unsigned short* __restrict__ B1,
                const float* __restrict__ W2p,
                const float* __restrict__ b2,
                float* __restrict__ outAng)
{
    __shared__ unsigned short Alds[32][136];   // 32 rows x K=128 (+8 pad)
    __shared__ float sbuf[32][8];              // angle accumulators

    const int  tid = threadIdx.x;
    const long bm  = (long)blockIdx.x * 32;

    if (tid < 256) ((float*)sbuf)[tid] = 0.f;

    // ---- stage A: x split [x_hi | x_lo | x_hi | 1 | 1] as bf16 ----
    {
        const int r   = tid >> 4;     // 0..31
        const int c16 = tid & 15;     // 16 groups of 8 k
        const float* jr = joints + (bm + r) * DIM;
        short8 s;
#pragma unroll
        for (int j = 0; j < 8; ++j) {
            const int k = c16 * 8 + j;
            unsigned short v;
            if (k >= 126) {
                v = 0x3F80;  // bf16(1.0)
            } else {
                const int ksrc = (k < 42) ? k : (k < 84 ? k - 42 : k - 84);
                const float x = jr[ksrc] - jr[ksrc % 3];
                const unsigned short hi = f2bf(x);
                v = (k >= 42 && k < 84) ? f2bf(x - bf2f(hi)) : hi;
            }
            s[j] = (short)v;
        }
        *((short8*)&Alds[r][c16 * 8]) = s;
    }
    __syncthreads();

    const int lane = tid & 63;
    const int w    = tid >> 6;     // wave 0..7
    const int g    = lane >> 4;    // 0..3
    const int lm   = lane & 15;

    // ---- x fragments (B-operand) from LDS ----
    short8 a[2][4];
#pragma unroll
    for (int mt = 0; mt < 2; ++mt)
#pragma unroll
        for (int ks = 0; ks < 4; ++ks)
            a[mt][ks] = *((const short8*)&Alds[mt * 16 + lm][ks * 32 + g * 8]);

    // angle partials: [mt][d-pair] as f32x2 (d = 0..7, col 7 is zero pad)
    f32x2 angp[2][4];
#pragma unroll
    for (int mt = 0; mt < 2; ++mt)
#pragma unroll
        for (int p = 0; p < 4; ++p) angp[mt][p] = (f32x2){0.f, 0.f};

    const short8* Bf = (const short8*)B1;
#pragma unroll
    for (int nt = 0; nt < 8; ++nt) {
        const int ntile = w * 8 + nt;
        f32x4 acc0 = (f32x4){0.f, 0.f, 0.f, 0.f};
        f32x4 acc1 = (f32x4){0.f, 0.f, 0.f, 0.f};
#pragma unroll
        for (int ks = 0; ks < 4; ++ks) {
            const short8 bfr = Bf[(ks * 64 + ntile) * 64 + lane];
            acc0 = __builtin_amdgcn_mfma_f32_16x16x32_bf16(bfr, a[0][ks], acc0, 0, 0, 0);
            acc1 = __builtin_amdgcn_mfma_f32_16x16x32_bf16(bfr, a[1][ks], acc1, 0, 0, 0);
        }
        // epilogue for this nt: lane holds h[n][m], n = ntile*16 + g*4 + r
#pragma unroll
        for (int r = 0; r < 4; ++r) {
            const long n = (long)ntile * 16 + g * 4 + r;
            const f32x4 wa = *((const f32x4*)(W2p + n * 8));
            const f32x4 wb = *((const f32x4*)(W2p + n * 8 + 4));
            const f32x2 w01 = (f32x2){wa[0], wa[1]};
            const f32x2 w23 = (f32x2){wa[2], wa[3]};
            const f32x2 w45 = (f32x2){wb[0], wb[1]};
            const f32x2 w67 = (f32x2){wb[2], wb[3]};
            const float h0 = fmaxf(acc0[r], 0.f);
            const float h1 = fmaxf(acc1[r], 0.f);
            const f32x2 h0v = (f32x2){h0, h0};
            const f32x2 h1v = (f32x2){h1, h1};
            angp[0][0] = __builtin_elementwise_fma(h0v, w01, angp[0][0]);
            angp[0][1] = __builtin_elementwise_fma(h0v, w23, angp[0][1]);
            angp[0][2] = __builtin_elementwise_fma(h0v, w45, angp[0][2]);
            angp[0][3] = __builtin_elementwise_fma(h0v, w67, angp[0][3]);
            angp[1][0] = __builtin_elementwise_fma(h1v, w01, angp[1][0]);
            angp[1][1] = __builtin_elementwise_fma(h1v, w23, angp[1][1]);
            angp[1][2] = __builtin_elementwise_fma(h1v, w45, angp[1][2]);
            angp[1][3] = __builtin_elementwise_fma(h1v, w67, angp[1][3]);
        }
    }

    // reduce across the 4 lane-groups (same m, different n ranges)
    float red[2][8];
#pragma unroll
    for (int mt = 0; mt < 2; ++mt)
#pragma unroll
        for (int p = 0; p < 4; ++p) {
            red[mt][p * 2 + 0] = angp[mt][p][0];
            red[mt][p * 2 + 1] = angp[mt][p][1];
        }
#pragma unroll
    for (int mt = 0; mt < 2; ++mt)
#pragma unroll
        for (int i = 0; i < 8; ++i) {
            float v = red[mt][i];
            v += __shfl_xor(v, 16, 64);
            v += __shfl_xor(v, 32, 64);
            red[mt][i] = v;
        }
    if (lane < 16) {
#pragma unroll
        for (int mt = 0; mt < 2; ++mt)
#pragma unroll
            for (int i = 0; i < 8; ++i)
                atomicAdd(&sbuf[mt * 16 + lane][i], red[mt][i]);
    }
    __syncthreads();

    if (tid < 256) {
        const int m = tid >> 3, d = tid & 7;
        if (d < 7)
            outAng[(bm + m) * 7 + d] = sbuf[m][d] + b2[d];
    }
}

// ---------------------------------------------------------------------------
// K2: per-row FK + Kabsch (f64 Jacobi), reads angles from d_out.
// ---------------------------------------------------------------------------
#define JROT(app, aqq, apq, arp, arq, v0p, v0q, v1p, v1q, v2p, v2q) do { \
    double _apq = (apq); \
    if (fabs(_apq) > 1e-300) { \
        double _tau = ((aqq) - (app)) / (2.0 * _apq); \
        double _t = ((_tau >= 0.0) ? 1.0 : -1.0) / (fabs(_tau) + sqrt(1.0 + _tau*_tau)); \
        double _c = 1.0 / sqrt(1.0 + _t*_t); \
        double _s = _t * _c; \
        (app) -= _t * _apq; \
        (aqq) += _t * _apq; \
        (apq) = 0.0; \
        { double _rp = (arp), _rq = (arq); \
          (arp) = _c*_rp - _s*_rq; (arq) = _s*_rp + _c*_rq; } \
        { double _v = (v0p); (v0p) = _c*_v - _s*(v0q); (v0q) = _s*_v + _c*(v0q); } \
        { double _v = (v1p); (v1p) = _c*_v - _s*(v1q); (v1q) = _s*_v + _c*(v1q); } \
        { double _v = (v2p); (v2p) = _c*_v - _s*(v2q); (v2q) = _s*_v + _c*(v2q); } \
    } \
} while (0)

#define SWAP_EIG(ea, eb, va0, vb0, va1, vb1, va2, vb2) do { \
    double _tm; \
    _tm = (ea); (ea) = (eb); (eb) = _tm; \
    _tm = (va0); (va0) = (vb0); (vb0) = _tm; \
    _tm = (va1); (va1) = (vb1); (vb1) = _tm; \
    _tm = (va2); (va2) = (vb2); (vb2) = _tm; \
} while (0)

__global__ __launch_bounds__(256)
void fk_kernel(const float* __restrict__ joints,
               const float* __restrict__ ang_in,
               float* __restrict__ out)
{
    const int b = blockIdx.x * 256 + threadIdx.x;
    if (b >= B_) return;

    const float* jr = joints + (long)b * DIM;
    const float j0x = jr[0], j0y = jr[1], j0z = jr[2];
    float q[DIM];
#pragma unroll
    for (int k = 0; k < NKPS; ++k) {
        q[3*k+0] = jr[3*k+0] - j0x;
        q[3*k+1] = jr[3*k+1] - j0y;
        q[3*k+2] = jr[3*k+2] - j0z;
    }

    float ang[NDOF];
#pragma unroll
    for (int d = 0; d < NDOF; ++d) ang[d] = ang_in[(long)b * NDOF + d];

    float R00=1.f,R01=0.f,R02=0.f, R10=0.f,R11=1.f,R12=0.f, R20=0.f,R21=0.f,R22=1.f;
    float px=0.f, py=0.f, pz=0.f;
    float Hr00=0.f,Hr01=0.f,Hr02=0.f,Hr10=0.f,Hr11=0.f,Hr12=0.f,Hr20=0.f,Hr21=0.f,Hr22=0.f;
    float sPx=0.f, sPy=0.f, sPz=0.f;
    const float LL[NDOF] = {0.333f,0.316f,0.384f,0.088f,0.107f,0.103f,0.1f};

#pragma unroll
    for (int j = 0; j < NDOF; ++j) {
        float s, c;
        sincosf(ang[j], &s, &c);
        if ((j & 1) == 0) {
            float a0=R00, a1=R01; R00 = c*a0 + s*a1; R01 = c*a1 - s*a0;
            float b0=R10, b1v=R11; R10 = c*b0 + s*b1v; R11 = c*b1v - s*b0;
            float c0=R20, c1=R21; R20 = c*c0 + s*c1; R21 = c*c1 - s*c0;
        } else {
            float a0=R00, a2=R02; R00 = c*a0 - s*a2; R02 = s*a0 + c*a2;
            float b0=R10, b2v=R12; R10 = c*b0 - s*b2v; R12 = s*b0 + c*b2v;
            float c0=R20, c2=R22; R20 = c*c0 - s*c2; R22 = s*c0 + c*c2;
        }
        px = fmaf(LL[j], R02, px);
        py = fmaf(LL[j], R12, py);
        pz = fmaf(LL[j], R22, pz);
        {
            const float qx = q[6*j+0], qy = q[6*j+1], qz = q[6*j+2];
            sPx += px; sPy += py; sPz += pz;
            Hr00 = fmaf(px, qx, Hr00); Hr01 = fmaf(px, qy, Hr01); Hr02 = fmaf(px, qz, Hr02);
            Hr10 = fmaf(py, qx, Hr10); Hr11 = fmaf(py, qy, Hr11); Hr12 = fmaf(py, qz, Hr12);
            Hr20 = fmaf(pz, qx, Hr20); Hr21 = fmaf(pz, qy, Hr21); Hr22 = fmaf(pz, qz, Hr22);
        }
        {
            const float ox = fmaf(0.05f, R00, px);
            const float oy = fmaf(0.05f, R10, py);
            const float oz = fmaf(0.05f, R20, pz);
            const float qx = q[6*j+3], qy = q[6*j+4], qz = q[6*j+5];
            sPx += ox; sPy += oy; sPz += oz;
            Hr00 = fmaf(ox, qx, Hr00); Hr01 = fmaf(ox, qy, Hr01); Hr02 = fmaf(ox, qz, Hr02);
            Hr10 = fmaf(oy, qx, Hr10); Hr11 = fmaf(oy, qy, Hr11); Hr12 = fmaf(oy, qz, Hr12);
            Hr20 = fmaf(oz, qx, Hr20); Hr21 = fmaf(oz, qy, Hr21); Hr22 = fmaf(oz, qz, Hr22);
        }
    }

    float sQx = 0.f, sQy = 0.f, sQz = 0.f;
#pragma unroll
    for (int n = 0; n < NKPS; ++n) { sQx += q[3*n+0]; sQy += q[3*n+1]; sQz += q[3*n+2]; }

    const double inv14 = 1.0 / 14.0;
    const double cpx = (double)sPx * inv14, cpy = (double)sPy * inv14, cpz = (double)sPz * inv14;
    const double cqx = (double)sQx * inv14, cqy = (double)sQy * inv14, cqz = (double)sQz * inv14;

    const double h00 = (double)Hr00 - 14.0*cpx*cqx, h01 = (double)Hr01 - 14.0*cpx*cqy, h02 = (double)Hr02 - 14.0*cpx*cqz;
    const double h10 = (double)Hr10 - 14.0*cpy*cqx, h11 = (double)Hr11 - 14.0*cpy*cqy, h12 = (double)Hr12 - 14.0*cpy*cqz;
    const double h20 = (double)Hr20 - 14.0*cpz*cqx, h21 = (double)Hr21 - 14.0*cpz*cqy, h22 = (double)Hr22 - 14.0*cpz*cqz;

    double m00 = h00*h00 + h10*h10 + h20*h20;
    double m01 = h00*h01 + h10*h11 + h20*h21;
    double m02 = h00*h02 + h10*h12 + h20*h22;
    double m11 = h01*h01 + h11*h11 + h21*h21;
    double m12 = h01*h02 + h11*h12 + h21*h22;
    double m22 = h02*h02 + h12*h12 + h22*h22;

    double v00=1.0, v01=0.0, v02=0.0;
    double v10=0.0, v11=1.0, v12=0.0;
    double v20=0.0, v21=0.0, v22=1.0;

#pragma unroll
    for (int sw = 0; sw < 5; ++sw) {
        JROT(m00, m11, m01, m02, m12, v00, v01, v10, v11, v20, v21);
        JROT(m00, m22, m02, m01, m12, v00, v02, v10, v12, v20, v22);
        JROT(m11, m22, m12, m01, m02, v01, v02, v11, v12, v21, v22);
    }

    double e0 = m00, e1 = m11, e2 = m22;
    if (e0 < e1) SWAP_EIG(e0, e1, v00, v01, v10, v11, v20, v21);
    if (e0 < e2) SWAP_EIG(e0, e2, v00, v02, v10, v12, v20, v22);
    if (e1 < e2) SWAP_EIG(e1, e2, v01, v02, v11, v12, v21, v22);

    const double s0 = sqrt(fmax(e0, 0.0));
    const double s1 = sqrt(fmax(e1, 0.0));
    const double s2 = sqrt(fmax(e2, 0.0));

    const double det = h00*(h11*h22 - h12*h21) - h01*(h10*h22 - h12*h20) + h02*(h10*h21 - h11*h20);
    const double dsg = (det >= 0.0) ? 1.0 : -1.0;

    const double tiny = 1e-30;
    const double g0 = 1.0 / fmax(s0, tiny);
    const double g1 = 1.0 / fmax(s1, tiny);
    const double g2 = dsg / fmax(s2, tiny);

    const double K00 = g0*v00*v00 + g1*v01*v01 + g2*v02*v02;
    const double K01 = g0*v00*v10 + g1*v01*v11 + g2*v02*v12;
    const double K02 = g0*v00*v20 + g1*v01*v21 + g2*v02*v22;
    const double K11 = g0*v10*v10 + g1*v11*v11 + g2*v12*v12;
    const double K12 = g0*v10*v20 + g1*v11*v21 + g2*v12*v22;
    const double K22 = g0*v20*v20 + g1*v21*v21 + g2*v22*v22;

    const double r00 = K00*h00 + K01*h01 + K02*h02;
    const double r01 = K00*h10 + K01*h11 + K02*h12;
    const double r02 = K00*h20 + K01*h21 + K02*h22;
    const double r10 = K01*h00 + K11*h01 + K12*h02;
    const double r11 = K01*h10 + K11*h11 + K12*h12;
    const double r12 = K01*h20 + K11*h21 + K12*h22;
    const double r20 = K02*h00 + K12*h01 + K22*h02;
    const double r21 = K02*h10 + K12*h11 + K22*h12;
    const double r22 = K02*h20 + K12*h21 + K22*h22;

    const double tx = cqx - (r00*cpx + r01*cpy + r02*cpz) + (double)j0x;
    const double ty = cqy - (r10*cpx + r11*cpy + r12*cpz) + (double)j0y;
    const double tz = cqz - (r20*cpx + r21*cpy + r22*cpz) + (double)j0z;

    float* po = out + (long)B_ * NDOF + (long)b * 16;
    po[0]  = (float)r00; po[1]  = (float)r01; po[2]  = (float)r02; po[3]  = (float)tx;
    po[4]  = (float)r10; po[5]  = (float)r11; po[6]  = (float)r12; po[7]  = (float)ty;
    po[8]  = (float)r20; po[9]  = (float)r21; po[10] = (float)r22; po[11] = (float)tz;
    po[12] = 0.f; po[13] = 0.f; po[14] = 0.f; po[15] = 1.f;
}

extern "C" void kernel_launch(void* const* d_in, const int* in_sizes, int n_in,
                              void* d_out, int out_size, void* d_ws, size_t ws_size,
                              hipStream_t stream) {
    const float* joints = (const float*)d_in[0];
    const float* W1     = (const float*)d_in[1];
    const float* b1     = (const float*)d_in[2];
    const float* W2     = (const float*)d_in[3];
    const float* b2     = (const float*)d_in[4];
    float* out = (float*)d_out;

    unsigned short* B1  = (unsigned short*)d_ws;                     // 256 KB
    float*          W2p = (float*)((char*)d_ws + 262144);            // 32 KB

    hipLaunchKernelGGL(prep_kernel, dim3(68), dim3(256), 0, stream,
                       W1, b1, W2, B1, W2p);

    hipLaunchKernelGGL(mlp_kernel, dim3(B_ / 32), dim3(512), 0, stream,
                       joints, B1, W2p, b2, out);

    hipLaunchKernelGGL(fk_kernel, dim3(B_ / 256), dim3(256), 0, stream,
                       joints, out, out);
}

// Round 4
// 48.781 us; speedup vs baseline: 7.3774x; 1.0360x over previous
//
#include <hip/hip_runtime.h>
#include <math.h>

typedef __attribute__((ext_vector_type(8))) short short8;
typedef __attribute__((ext_vector_type(4))) float f32x4;
typedef __attribute__((ext_vector_type(2))) float f32x2;

constexpr int B_   = 32768;
constexpr int NKPS = 14;
constexpr int DIM  = 42;
constexpr int H1_  = 1024;
constexpr int NDOF = 7;

__device__ __forceinline__ unsigned short f2bf(float f) {
    unsigned u = __float_as_uint(f);
    u += 0x7FFFu + ((u >> 16) & 1u);
    return (unsigned short)(u >> 16);
}
__device__ __forceinline__ float bf2f(unsigned short h) {
    return __uint_as_float(((unsigned)h) << 16);
}

// ---------------------------------------------------------------------------
// K0: pack B = [W1_hi ; W1_hi ; W1_lo ; b1_hi ; b1_lo] (K=128 x N=1024 bf16)
// in per-lane fragment order: B1[((ks*64+nt)*64+lane)*8+j] =
//   B[k = ks*32+(lane>>4)*8+j][n = nt*16+(lane&15)].
// Also pads W2 [1024][7] -> W2p [1024][8] f32.
// ---------------------------------------------------------------------------
__global__ __launch_bounds__(256)
void prep_kernel(const float* __restrict__ W1, const float* __restrict__ b1,
                 const float* __restrict__ W2,
                 unsigned short* __restrict__ B1, float* __restrict__ W2p)
{
    const int T = blockIdx.x * 256 + threadIdx.x;
    if (T < 16384) {
        const int lane  = T & 63;
        const int ntile = (T >> 6) & 63;
        const int ks    = T >> 12;
        const int n     = ntile * 16 + (lane & 15);
        const int kbase = ks * 32 + ((lane >> 4) << 3);
        short8 s;
#pragma unroll
        for (int j = 0; j < 8; ++j) {
            const int k = kbase + j;
            unsigned short r;
            if (k < 42) {
                r = f2bf(W1[k * H1_ + n]);
            } else if (k < 84) {
                r = f2bf(W1[(k - 42) * H1_ + n]);
            } else if (k < 126) {
                const float x = W1[(k - 84) * H1_ + n];
                const unsigned short hi = f2bf(x);
                r = f2bf(x - bf2f(hi));
            } else if (k == 126) {
                r = f2bf(b1[n]);
            } else {
                const float x = b1[n];
                const unsigned short hi = f2bf(x);
                r = f2bf(x - bf2f(hi));
            }
            s[j] = (short)r;
        }
        *((short8*)(B1 + (long)T * 8)) = s;
    } else if (T < 16384 + 1024) {
        const int n = T - 16384;
#pragma unroll
        for (int d = 0; d < 7; ++d) W2p[n * 8 + d] = W2[n * 7 + d];
        W2p[n * 8 + 7] = 0.f;
    }
}

// ---------------------------------------------------------------------------
// K1: MLP via MFMA, swapped operands -> C[n][m] so the 1024-wide hidden
// reduction is within-lane. B1 frags register-double-buffered; W2 staged
// in LDS (XOR-swizzled so the 4 lane-groups hit distinct bank quads).
// ---------------------------------------------------------------------------
__global__ __launch_bounds__(512, 4)
void mlp_kernel(const float* __restrict__ joints,
                const unsigned short* __restrict__ B1,
                const float* __restrict__ W2p,
                const float* __restrict__ b2,
                float* __restrict__ outAng)
{
    __shared__ unsigned short Alds[32][136];   // 32 rows x K=128 (+8 pad)
    __shared__ float sbuf[32][8];              // angle accumulators
    __shared__ float W2s[8192];                // 32 KB, swizzled [1024][8]

    const int  tid  = threadIdx.x;
    const long bm   = (long)blockIdx.x * 32;
    const int  lane = tid & 63;
    const int  w    = tid >> 6;     // wave 0..7
    const int  g    = lane >> 4;    // 0..3
    const int  lm   = lane & 15;

    // ---- issue first B1 fragment loads immediately (in flight during staging)
    const short8* Bf = (const short8*)B1;
    short8 bc[4];
#pragma unroll
    for (int ks = 0; ks < 4; ++ks)
        bc[ks] = Bf[(ks * 64 + w * 8) * 64 + lane];

    // ---- stage W2 (32 KB) into LDS with XOR swizzle ----
#pragma unroll
    for (int i = 0; i < 4; ++i) {
        const int a  = (i * 512 + tid) * 16;                 // byte addr
        const f32x4 v = *((const f32x4*)((const char*)W2p + a));
        const int sw = a ^ (((a >> 7) & 3) << 4);
        *((f32x4*)((char*)W2s + sw)) = v;
    }

    if (tid < 256) ((float*)sbuf)[tid] = 0.f;

    // ---- stage A: x split [x_hi | x_lo | x_hi | 1 | 1] as bf16 ----
    {
        const int r   = tid >> 4;     // 0..31
        const int c16 = tid & 15;     // 16 groups of 8 k
        const float* jr = joints + (bm + r) * DIM;
        short8 s;
#pragma unroll
        for (int j = 0; j < 8; ++j) {
            const int k = c16 * 8 + j;
            unsigned short v;
            if (k >= 126) {
                v = 0x3F80;  // bf16(1.0)
            } else {
                const int ksrc = (k < 42) ? k : (k < 84 ? k - 42 : k - 84);
                const float x = jr[ksrc] - jr[ksrc % 3];
                const unsigned short hi = f2bf(x);
                v = (k >= 42 && k < 84) ? f2bf(x - bf2f(hi)) : hi;
            }
            s[j] = (short)v;
        }
        *((short8*)&Alds[r][c16 * 8]) = s;
    }
    __syncthreads();

    // ---- x fragments (B-operand) from LDS ----
    short8 a[2][4];
#pragma unroll
    for (int mt = 0; mt < 2; ++mt)
#pragma unroll
        for (int ks = 0; ks < 4; ++ks)
            a[mt][ks] = *((const short8*)&Alds[mt * 16 + lm][ks * 32 + g * 8]);

    // angle partials: [mt][d-pair] as f32x2 (d = 0..7, col 7 is zero pad)
    f32x2 angp[2][4];
#pragma unroll
    for (int mt = 0; mt < 2; ++mt)
#pragma unroll
        for (int p = 0; p < 4; ++p) angp[mt][p] = (f32x2){0.f, 0.f};

#pragma unroll
    for (int nt = 0; nt < 8; ++nt) {
        // prefetch next nt's B1 fragments (one tile ahead)
        short8 bn[4];
        if (nt < 7) {
#pragma unroll
            for (int ks = 0; ks < 4; ++ks)
                bn[ks] = Bf[(ks * 64 + w * 8 + nt + 1) * 64 + lane];
        }

        f32x4 acc0 = (f32x4){0.f, 0.f, 0.f, 0.f};
        f32x4 acc1 = (f32x4){0.f, 0.f, 0.f, 0.f};
#pragma unroll
        for (int ks = 0; ks < 4; ++ks) {
            acc0 = __builtin_amdgcn_mfma_f32_16x16x32_bf16(bc[ks], a[0][ks], acc0, 0, 0, 0);
            acc1 = __builtin_amdgcn_mfma_f32_16x16x32_bf16(bc[ks], a[1][ks], acc1, 0, 0, 0);
        }

        // epilogue: lane holds h[n][m], n = ntile*16 + g*4 + r (W2 from LDS)
        const int ntile = w * 8 + nt;
#pragma unroll
        for (int r = 0; r < 4; ++r) {
            const int n  = ntile * 16 + g * 4 + r;
            const int ad = n * 32;
            const int sw = ad ^ (((ad >> 7) & 3) << 4);
            const f32x4 wa = *((const f32x4*)((const char*)W2s + sw));
            const f32x4 wb = *((const f32x4*)((const char*)W2s + (sw ^ 16)));
            const f32x2 w01 = (f32x2){wa[0], wa[1]};
            const f32x2 w23 = (f32x2){wa[2], wa[3]};
            const f32x2 w45 = (f32x2){wb[0], wb[1]};
            const f32x2 w67 = (f32x2){wb[2], wb[3]};
            const float h0 = fmaxf(acc0[r], 0.f);
            const float h1 = fmaxf(acc1[r], 0.f);
            const f32x2 h0v = (f32x2){h0, h0};
            const f32x2 h1v = (f32x2){h1, h1};
            angp[0][0] = __builtin_elementwise_fma(h0v, w01, angp[0][0]);
            angp[0][1] = __builtin_elementwise_fma(h0v, w23, angp[0][1]);
            angp[0][2] = __builtin_elementwise_fma(h0v, w45, angp[0][2]);
            angp[0][3] = __builtin_elementwise_fma(h0v, w67, angp[0][3]);
            angp[1][0] = __builtin_elementwise_fma(h1v, w01, angp[1][0]);
            angp[1][1] = __builtin_elementwise_fma(h1v, w23, angp[1][1]);
            angp[1][2] = __builtin_elementwise_fma(h1v, w45, angp[1][2]);
            angp[1][3] = __builtin_elementwise_fma(h1v, w67, angp[1][3]);
        }

        if (nt < 7) {
#pragma unroll
            for (int ks = 0; ks < 4; ++ks) bc[ks] = bn[ks];
        }
    }

    // reduce across the 4 lane-groups (same m, different n ranges)
    float red[2][8];
#pragma unroll
    for (int mt = 0; mt < 2; ++mt)
#pragma unroll
        for (int p = 0; p < 4; ++p) {
            red[mt][p * 2 + 0] = angp[mt][p][0];
            red[mt][p * 2 + 1] = angp[mt][p][1];
        }
#pragma unroll
    for (int mt = 0; mt < 2; ++mt)
#pragma unroll
        for (int i = 0; i < 8; ++i) {
            float v = red[mt][i];
            v += __shfl_xor(v, 16, 64);
            v += __shfl_xor(v, 32, 64);
            red[mt][i] = v;
        }
    if (lane < 16) {
#pragma unroll
        for (int mt = 0; mt < 2; ++mt)
#pragma unroll
            for (int i = 0; i < 8; ++i)
                atomicAdd(&sbuf[mt * 16 + lane][i], red[mt][i]);
    }
    __syncthreads();

    if (tid < 256) {
        const int m = tid >> 3, d = tid & 7;
        if (d < 7)
            outAng[(bm + m) * 7 + d] = sbuf[m][d] + b2[d];
    }
}

// ---------------------------------------------------------------------------
// K2: per-row FK + Kabsch (f64 Jacobi), reads angles from d_out.
// ---------------------------------------------------------------------------
#define JROT(app, aqq, apq, arp, arq, v0p, v0q, v1p, v1q, v2p, v2q) do { \
    double _apq = (apq); \
    if (fabs(_apq) > 1e-300) { \
        double _tau = ((aqq) - (app)) / (2.0 * _apq); \
        double _t = ((_tau >= 0.0) ? 1.0 : -1.0) / (fabs(_tau) + sqrt(1.0 + _tau*_tau)); \
        double _c = 1.0 / sqrt(1.0 + _t*_t); \
        double _s = _t * _c; \
        (app) -= _t * _apq; \
        (aqq) += _t * _apq; \
        (apq) = 0.0; \
        { double _rp = (arp), _rq = (arq); \
          (arp) = _c*_rp - _s*_rq; (arq) = _s*_rp + _c*_rq; } \
        { double _v = (v0p); (v0p) = _c*_v - _s*(v0q); (v0q) = _s*_v + _c*(v0q); } \
        { double _v = (v1p); (v1p) = _c*_v - _s*(v1q); (v1q) = _s*_v + _c*(v1q); } \
        { double _v = (v2p); (v2p) = _c*_v - _s*(v2q); (v2q) = _s*_v + _c*(v2q); } \
    } \
} while (0)

#define SWAP_EIG(ea, eb, va0, vb0, va1, vb1, va2, vb2) do { \
    double _tm; \
    _tm = (ea); (ea) = (eb); (eb) = _tm; \
    _tm = (va0); (va0) = (vb0); (vb0) = _tm; \
    _tm = (va1); (va1) = (vb1); (vb1) = _tm; \
    _tm = (va2); (va2) = (vb2); (vb2) = _tm; \
} while (0)

__global__ __launch_bounds__(256)
void fk_kernel(const float* __restrict__ joints,
               const float* __restrict__ ang_in,
               float* __restrict__ out)
{
    const int b = blockIdx.x * 256 + threadIdx.x;
    if (b >= B_) return;

    const float* jr = joints + (long)b * DIM;
    const float j0x = jr[0], j0y = jr[1], j0z = jr[2];
    float q[DIM];
#pragma unroll
    for (int k = 0; k < NKPS; ++k) {
        q[3*k+0] = jr[3*k+0] - j0x;
        q[3*k+1] = jr[3*k+1] - j0y;
        q[3*k+2] = jr[3*k+2] - j0z;
    }

    float ang[NDOF];
#pragma unroll
    for (int d = 0; d < NDOF; ++d) ang[d] = ang_in[(long)b * NDOF + d];

    float R00=1.f,R01=0.f,R02=0.f, R10=0.f,R11=1.f,R12=0.f, R20=0.f,R21=0.f,R22=1.f;
    float px=0.f, py=0.f, pz=0.f;
    float Hr00=0.f,Hr01=0.f,Hr02=0.f,Hr10=0.f,Hr11=0.f,Hr12=0.f,Hr20=0.f,Hr21=0.f,Hr22=0.f;
    float sPx=0.f, sPy=0.f, sPz=0.f;
    const float LL[NDOF] = {0.333f,0.316f,0.384f,0.088f,0.107f,0.103f,0.1f};

#pragma unroll
    for (int j = 0; j < NDOF; ++j) {
        float s, c;
        sincosf(ang[j], &s, &c);
        if ((j & 1) == 0) {
            float a0=R00, a1=R01; R00 = c*a0 + s*a1; R01 = c*a1 - s*a0;
            float b0=R10, b1v=R11; R10 = c*b0 + s*b1v; R11 = c*b1v - s*b0;
            float c0=R20, c1=R21; R20 = c*c0 + s*c1; R21 = c*c1 - s*c0;
        } else {
            float a0=R00, a2=R02; R00 = c*a0 - s*a2; R02 = s*a0 + c*a2;
            float b0=R10, b2v=R12; R10 = c*b0 - s*b2v; R12 = s*b0 + c*b2v;
            float c0=R20, c2=R22; R20 = c*c0 - s*c2; R22 = s*c0 + c*c2;
        }
        px = fmaf(LL[j], R02, px);
        py = fmaf(LL[j], R12, py);
        pz = fmaf(LL[j], R22, pz);
        {
            const float qx = q[6*j+0], qy = q[6*j+1], qz = q[6*j+2];
            sPx += px; sPy += py; sPz += pz;
            Hr00 = fmaf(px, qx, Hr00); Hr01 = fmaf(px, qy, Hr01); Hr02 = fmaf(px, qz, Hr02);
            Hr10 = fmaf(py, qx, Hr10); Hr11 = fmaf(py, qy, Hr11); Hr12 = fmaf(py, qz, Hr12);
            Hr20 = fmaf(pz, qx, Hr20); Hr21 = fmaf(pz, qy, Hr21); Hr22 = fmaf(pz, qz, Hr22);
        }
        {
            const float ox = fmaf(0.05f, R00, px);
            const float oy = fmaf(0.05f, R10, py);
            const float oz = fmaf(0.05f, R20, pz);
            const float qx = q[6*j+3], qy = q[6*j+4], qz = q[6*j+5];
            sPx += ox; sPy += oy; sPz += oz;
            Hr00 = fmaf(ox, qx, Hr00); Hr01 = fmaf(ox, qy, Hr01); Hr02 = fmaf(ox, qz, Hr02);
            Hr10 = fmaf(oy, qx, Hr10); Hr11 = fmaf(oy, qy, Hr11); Hr12 = fmaf(oy, qz, Hr12);
            Hr20 = fmaf(oz, qx, Hr20); Hr21 = fmaf(oz, qy, Hr21); Hr22 = fmaf(oz, qz, Hr22);
        }
    }

    float sQx = 0.f, sQy = 0.f, sQz = 0.f;
#pragma unroll
    for (int n = 0; n < NKPS; ++n) { sQx += q[3*n+0]; sQy += q[3*n+1]; sQz += q[3*n+2]; }

    const double inv14 = 1.0 / 14.0;
    const double cpx = (double)sPx * inv14, cpy = (double)sPy * inv14, cpz = (double)sPz * inv14;
    const double cqx = (double)sQx * inv14, cqy = (double)sQy * inv14, cqz = (double)sQz * inv14;

    const double h00 = (double)Hr00 - 14.0*cpx*cqx, h01 = (double)Hr01 - 14.0*cpx*cqy, h02 = (double)Hr02 - 14.0*cpx*cqz;
    const double h10 = (double)Hr10 - 14.0*cpy*cqx, h11 = (double)Hr11 - 14.0*cpy*cqy, h12 = (double)Hr12 - 14.0*cpy*cqz;
    const double h20 = (double)Hr20 - 14.0*cpz*cqx, h21 = (double)Hr21 - 14.0*cpz*cqy, h22 = (double)Hr22 - 14.0*cpz*cqz;

    double m00 = h00*h00 + h10*h10 + h20*h20;
    double m01 = h00*h01 + h10*h11 + h20*h21;
    double m02 = h00*h02 + h10*h12 + h20*h22;
    double m11 = h01*h01 + h11*h11 + h21*h21;
    double m12 = h01*h02 + h11*h12 + h21*h22;
    double m22 = h02*h02 + h12*h12 + h22*h22;

    double v00=1.0, v01=0.0, v02=0.0;
    double v10=0.0, v11=1.0, v12=0.0;
    double v20=0.0, v21=0.0, v22=1.0;

#pragma unroll
    for (int sw = 0; sw < 5; ++sw) {
        JROT(m00, m11, m01, m02, m12, v00, v01, v10, v11, v20, v21);
        JROT(m00, m22, m02, m01, m12, v00, v02, v10, v12, v20, v22);
        JROT(m11, m22, m12, m01, m02, v01, v02, v11, v12, v21, v22);
    }

    double e0 = m00, e1 = m11, e2 = m22;
    if (e0 < e1) SWAP_EIG(e0, e1, v00, v01, v10, v11, v20, v21);
    if (e0 < e2) SWAP_EIG(e0, e2, v00, v02, v10, v12, v20, v22);
    if (e1 < e2) SWAP_EIG(e1, e2, v01, v02, v11, v12, v21, v22);

    const double s0 = sqrt(fmax(e0, 0.0));
    const double s1 = sqrt(fmax(e1, 0.0));
    const double s2 = sqrt(fmax(e2, 0.0));

    const double det = h00*(h11*h22 - h12*h21) - h01*(h10*h22 - h12*h20) + h02*(h10*h21 - h11*h20);
    const double dsg = (det >= 0.0) ? 1.0 : -1.0;

    const double tiny = 1e-30;
    const double g0 = 1.0 / fmax(s0, tiny);
    const double g1 = 1.0 / fmax(s1, tiny);
    const double g2 = dsg / fmax(s2, tiny);

    const double K00 = g0*v00*v00 + g1*v01*v01 + g2*v02*v02;
    const double K01 = g0*v00*v10 + g1*v01*v11 + g2*v02*v12;
    const double K02 = g0*v00*v20 + g1*v01*v21 + g2*v02*v22;
    const double K11 = g0*v10*v10 + g1*v11*v11 + g2*v12*v12;
    const double K12 = g0*v10*v20 + g1*v11*v21 + g2*v12*v22;
    const double K22 = g0*v20*v20 + g1*v21*v21 + g2*v22*v22;

    const double r00 = K00*h00 + K01*h01 + K02*h02;
    const double r01 = K00*h10 + K01*h11 + K02*h12;
    const double r02 = K00*h20 + K01*h21 + K02*h22;
    const double r10 = K01*h00 + K11*h01 + K12*h02;
    const double r11 = K01*h10 + K11*h11 + K12*h12;
    const double r12 = K01*h20 + K11*h21 + K12*h22;
    const double r20 = K02*h00 + K12*h01 + K22*h02;
    const double r21 = K02*h10 + K12*h11 + K22*h12;
    const double r22 = K02*h20 + K12*h21 + K22*h22;

    const double tx = cqx - (r00*cpx + r01*cpy + r02*cpz) + (double)j0x;
    const double ty = cqy - (r10*cpx + r11*cpy + r12*cpz) + (double)j0y;
    const double tz = cqz - (r20*cpx + r21*cpy + r22*cpz) + (double)j0z;

    float* po = out + (long)B_ * NDOF + (long)b * 16;
    po[0]  = (float)r00; po[1]  = (float)r01; po[2]  = (float)r02; po[3]  = (float)tx;
    po[4]  = (float)r10; po[5]  = (float)r11; po[6]  = (float)r12; po[7]  = (float)ty;
    po[8]  = (float)r20; po[9]  = (float)r21; po[10] = (float)r22; po[11] = (float)tz;
    po[12] = 0.f; po[13] = 0.f; po[14] = 0.f; po[15] = 1.f;
}

extern "C" void kernel_launch(void* const* d_in, const int* in_sizes, int n_in,
                              void* d_out, int out_size, void* d_ws, size_t ws_size,
                              hipStream_t stream) {
    const float* joints = (const float*)d_in[0];
    const float* W1     = (const float*)d_in[1];
    const float* b1     = (const float*)d_in[2];
    const float* W2     = (const float*)d_in[3];
    const float* b2     = (const float*)d_in[4];
    float* out = (float*)d_out;

    unsigned short* B1  = (unsigned short*)d_ws;                     // 256 KB
    float*          W2p = (float*)((char*)d_ws + 262144);            // 32 KB

    hipLaunchKernelGGL(prep_kernel, dim3(68), dim3(256), 0, stream,
                       W1, b1, W2, B1, W2p);

    hipLaunchKernelGGL(mlp_kernel, dim3(B_ / 32), dim3(512), 0, stream,
                       joints, B1, W2p, b2, out);

    hipLaunchKernelGGL(fk_kernel, dim3(B_ / 256), dim3(256), 0, stream,
                       joints, out, out);
}